// Round 15
// baseline (116.221 us; speedup 1.0000x reference)
//
#include <hip/hip_runtime.h>

typedef __attribute__((ext_vector_type(8))) short bf16x8;
typedef __attribute__((ext_vector_type(4))) float f32x4;
typedef __attribute__((ext_vector_type(2))) unsigned int u32x2;
typedef __attribute__((ext_vector_type(8))) unsigned short ushort8v;

__device__ __forceinline__ unsigned short f2bf(float f) {
  unsigned int u = __float_as_uint(f);
  u += 0x7fffu + ((u >> 16) & 1u);  // round-to-nearest-even
  return (unsigned short)(u >> 16);
}

__device__ __forceinline__ void gload_lds16(const unsigned short* g, unsigned short* l) {
  __builtin_amdgcn_global_load_lds(
      (const __attribute__((address_space(1))) unsigned int*)g,
      (__attribute__((address_space(3))) unsigned int*)l,
      16, 0, 0);
}

// ---------------- fused fp32 -> bf16 convert: 8 elems/thread/iter, 16B stores ----------------
__global__ void cvt_all(const float* __restrict__ x, const float* __restrict__ wq,
                        const float* __restrict__ wp, unsigned short* __restrict__ dst) {
  const int n1 = 4096 * 1024 / 8, n2 = 3072 * 1024 / 8, n3 = 1024 * 1024 / 8;
  int stride = gridDim.x * blockDim.x;
  for (int i = blockIdx.x * blockDim.x + threadIdx.x; i < n1 + n2 + n3; i += stride) {
    const float* s; int j;
    if (i < n1)           { s = x;  j = i; }
    else if (i < n1 + n2) { s = wq; j = i - n1; }
    else                  { s = wp; j = i - n1 - n2; }
    float4 a = ((const float4*)s)[j * 2];
    float4 b = ((const float4*)s)[j * 2 + 1];
    ushort8v o;
    o[0] = f2bf(a.x); o[1] = f2bf(a.y); o[2] = f2bf(a.z); o[3] = f2bf(a.w);
    o[4] = f2bf(b.x); o[5] = f2bf(b.y); o[6] = f2bf(b.z); o[7] = f2bf(b.w);
    ((ushort8v*)dst)[i] = o;
  }
}

// ---------------- 128x64-tile gemm_bt: 2 waves, SAME proven 2-barrier inner loop ----------------
// Identical per-wave work density to the frozen 128^2 version (16 MFMA / 8 ds_read per iter,
// same chunk-XOR swizzle algebra: slot rows r0+32j keep (r>>1)&3 invariant). Halved blocks
// give 2x barrier domains per CU -> stage drains of co-resident blocks hide each other.
// A-tile [128][32] (8KB), B-tile [64][32] (4KB); 128 threads.
__device__ __forceinline__ void gemm128x64_bt(const unsigned short* __restrict__ A,
                                              const unsigned short* __restrict__ Bt,
                                              unsigned short* As, unsigned short* Bs,
                                              int tm, int tn, f32x4 acc[4][4]) {
  const int K = 1024;
  int tid = threadIdx.x;         // 0..127
  int w = tid >> 6, l = tid & 63;
  int g = l >> 4, c = l & 15;

  int r0 = tid >> 2;                                // 0..31 (slots add 32)
  int skoff = (((tid & 3) ^ ((r0 >> 1) & 3)) * 8);  // pre-swizzled source k-offset
  const unsigned short* gA = A + (size_t)(tm * 128 + r0) * K + skoff;
  const unsigned short* gB = Bt + (size_t)(tn * 64 + r0) * K + skoff;
  unsigned short* lA = As + tid * 8;   // linear LDS dest; slots at +1024 ushorts
  unsigned short* lB = Bs + tid * 8;

  int rx = (c >> 1) & 3;
  int arow = w * 64 + c;   // + mi*16
  int brow = c;            // + ni*16

  for (int k0 = 0; k0 < K; k0 += 32) {
    gload_lds16(gA, lA);
    gload_lds16(gA + 32 * K, lA + 1024);
    gload_lds16(gA + 64 * K, lA + 2048);
    gload_lds16(gA + 96 * K, lA + 3072);
    gload_lds16(gB, lB);
    gload_lds16(gB + 32 * K, lB + 1024);
    gA += 32; gB += 32;
    __syncthreads();
    bf16x8 af[4], bfr[4];
#pragma unroll
    for (int mi = 0; mi < 4; ++mi)
      af[mi] = *(const bf16x8*)((const char*)As + (arow + mi * 16) * 64 + ((g ^ rx) << 4));
#pragma unroll
    for (int ni = 0; ni < 4; ++ni)
      bfr[ni] = *(const bf16x8*)((const char*)Bs + (brow + ni * 16) * 64 + ((g ^ rx) << 4));
#pragma unroll
    for (int mi = 0; mi < 4; ++mi)
#pragma unroll
      for (int ni = 0; ni < 4; ++ni)
        acc[mi][ni] = __builtin_amdgcn_mfma_f32_16x16x32_bf16(af[mi], bfr[ni], acc[mi][ni], 0, 0, 0);
    __syncthreads();
  }
}

// ---------------- QKV projection: 1536 blocks x 128 thr (6 domains/CU) ----------------
__global__ __launch_bounds__(128) void qkv_gemm(const unsigned short* __restrict__ xb,
                                                const unsigned short* __restrict__ wb,
                                                unsigned short* __restrict__ Qp,
                                                unsigned short* __restrict__ Kp,
                                                unsigned short* __restrict__ Vt) {
  __shared__ unsigned short As[128 * 32];
  __shared__ unsigned short Bs[64 * 32];
  f32x4 acc[4][4];
#pragma unroll
  for (int i = 0; i < 4; ++i)
#pragma unroll
    for (int j = 0; j < 4; ++j) acc[i][j] = f32x4{0.f, 0.f, 0.f, 0.f};
  int id = (blockIdx.x & 7) * 192 + (blockIdx.x >> 3);  // bijective (1536 % 8 == 0)
  int tm = id / 48, tn = id % 48;
  gemm128x64_bt(xb, wb, As, Bs, tm, tn, acc);

  int tid = threadIdx.x;
  int w = tid >> 6, l = tid & 63;
  int g = l >> 4, c = l & 15;
  const float QSCALE = 0.125f * 1.44269504088896f;  // hd^-0.5 * log2(e)
#pragma unroll
  for (int mi = 0; mi < 4; ++mi)
#pragma unroll
    for (int ni = 0; ni < 4; ++ni)
#pragma unroll
      for (int r = 0; r < 4; ++r) {
        int row = tm * 128 + w * 64 + mi * 16 + g * 4 + r;  // 0..4095
        int col = tn * 64 + ni * 16 + c;                    // 0..3071
        int b = row >> 11, seq = row & 2047;
        int t = col >> 10;
        int h = (col >> 6) & 15, d = col & 63;
        size_t bh = (size_t)b * 16 + h;
        float v = acc[mi][ni][r];
        if (t == 0)      Qp[(bh * 2048 + seq) * 64 + d] = f2bf(v * QSCALE);
        else if (t == 1) Kp[(bh * 2048 + seq) * 64 + d] = f2bf(v);
        else             Vt[(bh * 64 + d) * 2048 + seq] = f2bf(v);          // transposed V
      }
}

// ---------------- block-causal flash attention (R14 proven): K-sliced waves ----------------
__global__ __launch_bounds__(256, 3) void attn_fa(const unsigned short* __restrict__ Qp,
                                                  const unsigned short* __restrict__ Kp,
                                                  const unsigned short* __restrict__ Vt,
                                                  unsigned short* __restrict__ attn) {
  __shared__ unsigned short Ks[2][4096];   // [buf][64 seq x 64 d], swizzled; reused as Ored
  __shared__ unsigned short Vs[2][4096];   // [buf][64 d x 64 seq], swizzled; reused as lpred
  int tid = threadIdx.x;
  int w = tid >> 6, l = tid & 63;
  int g = l >> 4, c = l & 15;

  int idx = blockIdx.x;
  int pos = idx >> 3;                    // 0..127
  int qb = 31 - (pos >> 2);              // heavy blocks dispatch first
  int bh = (idx & 7) + 8 * (pos & 3);    // 4 bh per XCD slot (K/V L2 locality)

  const unsigned short* Qbh = Qp + (size_t)bh * 2048 * 64;
  const unsigned short* Kbh = Kp + (size_t)bh * 2048 * 64;
  const unsigned short* Vbh = Vt + (size_t)bh * 64 * 2048;

  int rowA, colA, rowB, colB;
  { int L = tid * 16;         int P = L ^ (((L >> 7) & 7) << 4); rowA = P >> 7; colA = (P & 127) >> 1; }
  { int L = (tid + 256) * 16; int P = L ^ (((L >> 7) & 7) << 4); rowB = P >> 7; colB = (P & 127) >> 1; }
  const unsigned short* gKA = Kbh + rowA * 64 + colA;            // + kb*4096
  const unsigned short* gKB = Kbh + rowB * 64 + colB;
  const unsigned short* gVA = Vbh + (size_t)rowA * 2048 + colA;  // + kb*64
  const unsigned short* gVB = Vbh + (size_t)rowB * 2048 + colB;

#define STAGE(buf, kb)                                              \
  do {                                                              \
    gload_lds16(gKA + (kb) * 4096, &Ks[(buf)][w * 512]);            \
    gload_lds16(gKB + (kb) * 4096, &Ks[(buf)][w * 512 + 2048]);     \
    gload_lds16(gVA + (kb) * 64,  &Vs[(buf)][w * 512]);             \
    gload_lds16(gVB + (kb) * 64,  &Vs[(buf)][w * 512 + 2048]);      \
  } while (0)

  // ALL 64 q-rows hoisted (loop-invariant)
  bf16x8 qf[4][2];
#pragma unroll
  for (int qg = 0; qg < 4; ++qg) {
    size_t qrow = (size_t)qb * 64 + qg * 16 + c;
    qf[qg][0] = *(const bf16x8*)(Qbh + qrow * 64 + 8 * g);
    qf[qg][1] = *(const bf16x8*)(Qbh + qrow * 64 + 32 + 8 * g);
  }

  float lp4[4] = {0.f, 0.f, 0.f, 0.f};
  f32x4 o[4][4];
#pragma unroll
  for (int qg = 0; qg < 4; ++qg)
#pragma unroll
    for (int df = 0; df < 4; ++df) o[qg][df] = f32x4{0.f, 0.f, 0.f, 0.f};

  int xorv = c & 7;
  int krow = w * 16 + c;

  int cur = 0;
  STAGE(0, 0);
  __syncthreads();
  for (int kb = 0; kb <= qb; ++kb) {
    if (kb < qb) STAGE(1 - cur, kb + 1);

    const char* Kb = (const char*)&Ks[cur][0];
    const char* Vb = (const char*)&Vs[cur][0];
    bf16x8 kf0 = *(const bf16x8*)(Kb + krow * 128 + ((g ^ xorv) * 16));
    bf16x8 kf1 = *(const bf16x8*)(Kb + krow * 128 + (((4 + g) ^ xorv) * 16));
    u32x2 vf[4];
#pragma unroll
    for (int df = 0; df < 4; ++df)
      vf[df] = *(const u32x2*)(Vb + (df * 16 + c) * 128 + (((2 * w + (g >> 1)) ^ xorv) * 16) + 8 * (g & 1));
    u32x2 pa[4];
#pragma unroll
    for (int qg = 0; qg < 4; ++qg) {
      f32x4 s4 = f32x4{0.f, 0.f, 0.f, 0.f};
      s4 = __builtin_amdgcn_mfma_f32_16x16x32_bf16(kf0, qf[qg][0], s4, 0, 0, 0);
      s4 = __builtin_amdgcn_mfma_f32_16x16x32_bf16(kf1, qf[qg][1], s4, 0, 0, 0);
      float p0 = __builtin_amdgcn_exp2f(s4[0]);
      float p1 = __builtin_amdgcn_exp2f(s4[1]);
      float p2 = __builtin_amdgcn_exp2f(s4[2]);
      float p3 = __builtin_amdgcn_exp2f(s4[3]);
      lp4[qg] += (p0 + p1) + (p2 + p3);
      unsigned int w0, w1;
      asm("v_cvt_pk_bf16_f32 %0, %1, %2" : "=v"(w0) : "v"(p0), "v"(p1));
      asm("v_cvt_pk_bf16_f32 %0, %1, %2" : "=v"(w1) : "v"(p2), "v"(p3));
      pa[qg][0] = w0; pa[qg][1] = w1;
    }
#pragma unroll
    for (int qg = 0; qg < 4; ++qg)
#pragma unroll
      for (int df = 0; df < 4; ++df)
        asm("v_mfma_f32_16x16x16_bf16 %0, %1, %2, %0"
            : "+v"(o[qg][df]) : "v"(pa[qg]), "v"(vf[df]));
    __syncthreads();
    cur ^= 1;
  }
#undef STAGE

  // ---- cross-wave reduction (Ks/Vs reused) ----
  float* Ored  = (float*)&Ks[0][0];   // [64 q][64 d] f32
  float* lpred = (float*)&Vs[0][0];   // [4 w][64 q] f32

  float lpw[4];
#pragma unroll
  for (int qg = 0; qg < 4; ++qg) {
    float v = lp4[qg];
    v += __shfl_xor(v, 16);
    v += __shfl_xor(v, 32);
    lpw[qg] = v;
  }
  if (g == 0) {
#pragma unroll
    for (int qg = 0; qg < 4; ++qg) lpred[w * 64 + qg * 16 + c] = lpw[qg];
  }
  for (int ww = 0; ww < 4; ++ww) {
    if (w == ww) {
#pragma unroll
      for (int qg = 0; qg < 4; ++qg)
#pragma unroll
        for (int df = 0; df < 4; ++df)
#pragma unroll
          for (int r = 0; r < 4; ++r) {
            int q = qg * 16 + 4 * g + r, d = df * 16 + c;
            if (ww == 0) Ored[q * 64 + d] = o[qg][df][r];
            else         Ored[q * 64 + d] += o[qg][df][r];
          }
    }
    __syncthreads();
  }

  float inv[4];
#pragma unroll
  for (int r = 0; r < 4; ++r) {
    int q = w * 16 + g * 4 + r;
    float s = (lpred[q] + lpred[64 + q]) + (lpred[128 + q] + lpred[192 + q]);
    inv[r] = __builtin_amdgcn_rcpf(s);
  }
  int b = bh >> 4, h = bh & 15;
#pragma unroll
  for (int df = 0; df < 4; ++df)
#pragma unroll
    for (int r = 0; r < 4; ++r) {
      int q = w * 16 + g * 4 + r;
      int row = qb * 64 + q;
      int colc = h * 64 + df * 16 + c;
      attn[((size_t)b * 2048 + row) * 1024 + colc] = f2bf(Ored[q * 64 + df * 16 + c] * inv[r]);
    }
}

// ---------------- output projection + bias: 512 blocks x 128 thr (2 domains/CU) ----------------
__global__ __launch_bounds__(128) void proj_gemm(const unsigned short* __restrict__ attn,
                                                 const unsigned short* __restrict__ wpb,
                                                 const float* __restrict__ bias,
                                                 float* __restrict__ out) {
  __shared__ unsigned short As[128 * 32];
  __shared__ unsigned short Bs[64 * 32];
  f32x4 acc[4][4];
#pragma unroll
  for (int i = 0; i < 4; ++i)
#pragma unroll
    for (int j = 0; j < 4; ++j) acc[i][j] = f32x4{0.f, 0.f, 0.f, 0.f};
  int id = (blockIdx.x & 7) * 64 + (blockIdx.x >> 3);  // bijective (512 % 8 == 0)
  int tm = id / 16, tn = id % 16;
  gemm128x64_bt(attn, wpb, As, Bs, tm, tn, acc);

  int tid = threadIdx.x;
  int w = tid >> 6, l = tid & 63;
  int g = l >> 4, c = l & 15;
#pragma unroll
  for (int mi = 0; mi < 4; ++mi)
#pragma unroll
    for (int ni = 0; ni < 4; ++ni)
#pragma unroll
      for (int r = 0; r < 4; ++r) {
        int row = tm * 128 + w * 64 + mi * 16 + g * 4 + r;
        int col = tn * 64 + ni * 16 + c;
        out[(size_t)row * 1024 + col] = acc[mi][ni][r] + bias[col];
      }
}

extern "C" void kernel_launch(void* const* d_in, const int* in_sizes, int n_in,
                              void* d_out, int out_size, void* d_ws, size_t ws_size,
                              hipStream_t stream) {
  (void)in_sizes; (void)n_in; (void)out_size; (void)ws_size;
  const float* x      = (const float*)d_in[0];  // [2,2048,1024]
  const float* w_qkv  = (const float*)d_in[1];  // [3072,1024]
  const float* w_proj = (const float*)d_in[2];  // [1024,1024]
  const float* b_proj = (const float*)d_in[3];  // [1024]
  float* out = (float*)d_out;

  unsigned short* xb    = (unsigned short*)d_ws;          // 4096*1024
  unsigned short* wqkvb = xb + 4096 * 1024;               // 3072*1024
  unsigned short* wpb   = wqkvb + 3072 * 1024;            // 1024*1024
  unsigned short* Qp    = wpb + 1024 * 1024;              // 32*2048*64
  unsigned short* Kp    = Qp + 32 * 2048 * 64;            // 32*2048*64
  unsigned short* Vt    = Kp + 32 * 2048 * 64;            // 32*64*2048
  unsigned short* attn  = Vt + 32 * 64 * 2048;            // 4096*1024

  cvt_all<<<1024, 256, 0, stream>>>(x, w_qkv, w_proj, xb);
  qkv_gemm<<<1536, 128, 0, stream>>>(xb, wqkvb, Qp, Kp, Vt);
  attn_fa<<<1024, 256, 0, stream>>>(Qp, Kp, Vt, attn);
  proj_gemm<<<512, 128, 0, stream>>>(attn, wpb, b_proj, out);
}

// Round 16
// 109.057 us; speedup vs baseline: 1.0657x; 1.0657x over previous
//
#include <hip/hip_runtime.h>

typedef __attribute__((ext_vector_type(8))) short bf16x8;
typedef __attribute__((ext_vector_type(4))) float f32x4;
typedef __attribute__((ext_vector_type(2))) unsigned int u32x2;
typedef __attribute__((ext_vector_type(8))) unsigned short ushort8v;

__device__ __forceinline__ unsigned short f2bf(float f) {
  unsigned int u = __float_as_uint(f);
  u += 0x7fffu + ((u >> 16) & 1u);  // round-to-nearest-even
  return (unsigned short)(u >> 16);
}

__device__ __forceinline__ void gload_lds16(const unsigned short* g, unsigned short* l) {
  __builtin_amdgcn_global_load_lds(
      (const __attribute__((address_space(1))) unsigned int*)g,
      (__attribute__((address_space(3))) unsigned int*)l,
      16, 0, 0);
}

// ---------------- fused fp32 -> bf16 convert: 8 elems/thread/iter, 16B stores ----------------
__global__ void cvt_all(const float* __restrict__ x, const float* __restrict__ wq,
                        const float* __restrict__ wp, unsigned short* __restrict__ dst) {
  const int n1 = 4096 * 1024 / 8, n2 = 3072 * 1024 / 8, n3 = 1024 * 1024 / 8;
  int stride = gridDim.x * blockDim.x;
  for (int i = blockIdx.x * blockDim.x + threadIdx.x; i < n1 + n2 + n3; i += stride) {
    const float* s; int j;
    if (i < n1)           { s = x;  j = i; }
    else if (i < n1 + n2) { s = wq; j = i - n1; }
    else                  { s = wp; j = i - n1 - n2; }
    float4 a = ((const float4*)s)[j * 2];
    float4 b = ((const float4*)s)[j * 2 + 1];
    ushort8v o;
    o[0] = f2bf(a.x); o[1] = f2bf(a.y); o[2] = f2bf(a.z); o[3] = f2bf(a.w);
    o[4] = f2bf(b.x); o[5] = f2bf(b.y); o[6] = f2bf(b.z); o[7] = f2bf(b.w);
    ((ushort8v*)dst)[i] = o;
  }
}

// ---------------- 128x128 gemm_bt (PROVEN 2-barrier structure, chunk-XOR) — FROZEN ----------
__device__ __forceinline__ void gemm128_bt(const unsigned short* __restrict__ A,
                                           const unsigned short* __restrict__ Bt,
                                           unsigned short* As, unsigned short* Bs,
                                           int tm, int tn, f32x4 acc[4][4]) {
  const int K = 1024;
  int tid = threadIdx.x;
  int w = tid >> 6, l = tid & 63;
  int wr = w >> 1, wc = w & 1;
  int g = l >> 4, c = l & 15;

  int srow = w * 32 + (l >> 2);
  int skoff = (((l & 3) ^ ((srow >> 1) & 3)) * 8);  // pre-swizzled source k-offset
  const unsigned short* gA = A + (size_t)(tm * 128 + srow) * K + skoff;
  const unsigned short* gB = Bt + (size_t)(tn * 128 + srow) * K + skoff;
  unsigned short* lA = As + (w * 32) * 32;  // wave-uniform LDS base (linear dest)
  unsigned short* lB = Bs + (w * 32) * 32;

  int rx = (c >> 1) & 3;
  int arow = wr * 64 + c;
  int brow = wc * 64 + c;

  for (int k0 = 0; k0 < K; k0 += 32) {
    gload_lds16(gA, lA);
    gload_lds16(gA + 16 * K, lA + 16 * 32);
    gload_lds16(gB, lB);
    gload_lds16(gB + 16 * K, lB + 16 * 32);
    gA += 32; gB += 32;
    __syncthreads();
    bf16x8 af[4], bfr[4];
#pragma unroll
    for (int mi = 0; mi < 4; ++mi)
      af[mi] = *(const bf16x8*)((const char*)As + (arow + mi * 16) * 64 + ((g ^ rx) << 4));
#pragma unroll
    for (int ni = 0; ni < 4; ++ni)
      bfr[ni] = *(const bf16x8*)((const char*)Bs + (brow + ni * 16) * 64 + ((g ^ rx) << 4));
#pragma unroll
    for (int mi = 0; mi < 4; ++mi)
#pragma unroll
      for (int ni = 0; ni < 4; ++ni)
        acc[mi][ni] = __builtin_amdgcn_mfma_f32_16x16x32_bf16(af[mi], bfr[ni], acc[mi][ni], 0, 0, 0);
    __syncthreads();
  }
}

// ---------------- QKV projection: scatter into Q (scaled), K, V^T ----------------
__global__ __launch_bounds__(256) void qkv_gemm(const unsigned short* __restrict__ xb,
                                                const unsigned short* __restrict__ wb,
                                                unsigned short* __restrict__ Qp,
                                                unsigned short* __restrict__ Kp,
                                                unsigned short* __restrict__ Vt) {
  __shared__ unsigned short As[128 * 32];
  __shared__ unsigned short Bs[128 * 32];
  f32x4 acc[4][4];
#pragma unroll
  for (int i = 0; i < 4; ++i)
#pragma unroll
    for (int j = 0; j < 4; ++j) acc[i][j] = f32x4{0.f, 0.f, 0.f, 0.f};
  int id = (blockIdx.x & 7) * 96 + (blockIdx.x >> 3);  // bijective (768 % 8 == 0)
  int tm = id / 24, tn = id % 24;
  gemm128_bt(xb, wb, As, Bs, tm, tn, acc);

  int tid = threadIdx.x;
  int w = tid >> 6, l = tid & 63;
  int wr = w >> 1, wc = w & 1;
  int g = l >> 4, c = l & 15;
  const float QSCALE = 0.125f * 1.44269504088896f;  // hd^-0.5 * log2(e)
#pragma unroll
  for (int mi = 0; mi < 4; ++mi)
#pragma unroll
    for (int ni = 0; ni < 4; ++ni)
#pragma unroll
      for (int r = 0; r < 4; ++r) {
        int row = tm * 128 + wr * 64 + mi * 16 + g * 4 + r;   // 0..4095
        int col = tn * 128 + wc * 64 + ni * 16 + c;           // 0..3071
        int b = row >> 11, seq = row & 2047;
        int t = col >> 10;
        int h = (col >> 6) & 15, d = col & 63;
        size_t bh = (size_t)b * 16 + h;
        float v = acc[mi][ni][r];
        if (t == 0)      Qp[(bh * 2048 + seq) * 64 + d] = f2bf(v * QSCALE);
        else if (t == 1) Kp[(bh * 2048 + seq) * 64 + d] = f2bf(v);
        else             Vt[(bh * 64 + d) * 2048 + seq] = f2bf(v);           // transposed V
      }
}

// ---------------- block-causal flash attention: K-SLICED waves (R14 proven) ----------------
// Wave w owns k-rows [16w,16w+16) of each tile for ALL 64 q-rows. Swapped QK^T puts
// P[q=c][k] lane-local -> cvt_pk -> x16-MFMA A-frags (no LDS round-trip). Per-wave
// partial O/denom over its k-slice; cross-wave LDS reduction after the loop.
__global__ __launch_bounds__(256, 3) void attn_fa(const unsigned short* __restrict__ Qp,
                                                  const unsigned short* __restrict__ Kp,
                                                  const unsigned short* __restrict__ Vt,
                                                  unsigned short* __restrict__ attn) {
  __shared__ unsigned short Ks[2][4096];   // [buf][64 seq x 64 d], swizzled; reused as Ored
  __shared__ unsigned short Vs[2][4096];   // [buf][64 d x 64 seq], swizzled; reused as lpred
  int tid = threadIdx.x;
  int w = tid >> 6, l = tid & 63;
  int g = l >> 4, c = l & 15;

  int idx = blockIdx.x;
  int pos = idx >> 3;                    // 0..127
  int qb = 31 - (pos >> 2);              // heavy blocks dispatch first
  int bh = (idx & 7) + 8 * (pos & 3);    // 4 bh per XCD slot (K/V L2 locality)

  const unsigned short* Qbh = Qp + (size_t)bh * 2048 * 64;
  const unsigned short* Kbh = Kp + (size_t)bh * 2048 * 64;
  const unsigned short* Vbh = Vt + (size_t)bh * 64 * 2048;

  int rowA, colA, rowB, colB;
  { int L = tid * 16;         int P = L ^ (((L >> 7) & 7) << 4); rowA = P >> 7; colA = (P & 127) >> 1; }
  { int L = (tid + 256) * 16; int P = L ^ (((L >> 7) & 7) << 4); rowB = P >> 7; colB = (P & 127) >> 1; }
  const unsigned short* gKA = Kbh + rowA * 64 + colA;            // + kb*4096
  const unsigned short* gKB = Kbh + rowB * 64 + colB;
  const unsigned short* gVA = Vbh + (size_t)rowA * 2048 + colA;  // + kb*64
  const unsigned short* gVB = Vbh + (size_t)rowB * 2048 + colB;

#define STAGE(buf, kb)                                              \
  do {                                                              \
    gload_lds16(gKA + (kb) * 4096, &Ks[(buf)][w * 512]);            \
    gload_lds16(gKB + (kb) * 4096, &Ks[(buf)][w * 512 + 2048]);     \
    gload_lds16(gVA + (kb) * 64,  &Vs[(buf)][w * 512]);             \
    gload_lds16(gVB + (kb) * 64,  &Vs[(buf)][w * 512 + 2048]);      \
  } while (0)

  // ALL 64 q-rows hoisted (loop-invariant)
  bf16x8 qf[4][2];
#pragma unroll
  for (int qg = 0; qg < 4; ++qg) {
    size_t qrow = (size_t)qb * 64 + qg * 16 + c;
    qf[qg][0] = *(const bf16x8*)(Qbh + qrow * 64 + 8 * g);
    qf[qg][1] = *(const bf16x8*)(Qbh + qrow * 64 + 32 + 8 * g);
  }

  float lp4[4] = {0.f, 0.f, 0.f, 0.f};
  f32x4 o[4][4];
#pragma unroll
  for (int qg = 0; qg < 4; ++qg)
#pragma unroll
    for (int df = 0; df < 4; ++df) o[qg][df] = f32x4{0.f, 0.f, 0.f, 0.f};

  int xorv = c & 7;
  int krow = w * 16 + c;

  int cur = 0;
  STAGE(0, 0);
  __syncthreads();
  for (int kb = 0; kb <= qb; ++kb) {
    if (kb < qb) STAGE(1 - cur, kb + 1);

    const char* Kb = (const char*)&Ks[cur][0];
    const char* Vb = (const char*)&Vs[cur][0];
    bf16x8 kf0 = *(const bf16x8*)(Kb + krow * 128 + ((g ^ xorv) * 16));
    bf16x8 kf1 = *(const bf16x8*)(Kb + krow * 128 + (((4 + g) ^ xorv) * 16));
    u32x2 vf[4];
#pragma unroll
    for (int df = 0; df < 4; ++df)
      vf[df] = *(const u32x2*)(Vb + (df * 16 + c) * 128 + (((2 * w + (g >> 1)) ^ xorv) * 16) + 8 * (g & 1));
    u32x2 pa[4];
#pragma unroll
    for (int qg = 0; qg < 4; ++qg) {
      f32x4 s4 = f32x4{0.f, 0.f, 0.f, 0.f};
      s4 = __builtin_amdgcn_mfma_f32_16x16x32_bf16(kf0, qf[qg][0], s4, 0, 0, 0);
      s4 = __builtin_amdgcn_mfma_f32_16x16x32_bf16(kf1, qf[qg][1], s4, 0, 0, 0);
      float p0 = __builtin_amdgcn_exp2f(s4[0]);
      float p1 = __builtin_amdgcn_exp2f(s4[1]);
      float p2 = __builtin_amdgcn_exp2f(s4[2]);
      float p3 = __builtin_amdgcn_exp2f(s4[3]);
      lp4[qg] += (p0 + p1) + (p2 + p3);
      unsigned int w0, w1;
      asm("v_cvt_pk_bf16_f32 %0, %1, %2" : "=v"(w0) : "v"(p0), "v"(p1));
      asm("v_cvt_pk_bf16_f32 %0, %1, %2" : "=v"(w1) : "v"(p2), "v"(p3));
      pa[qg][0] = w0; pa[qg][1] = w1;
    }
#pragma unroll
    for (int qg = 0; qg < 4; ++qg)
#pragma unroll
      for (int df = 0; df < 4; ++df)
        asm("v_mfma_f32_16x16x16_bf16 %0, %1, %2, %0"
            : "+v"(o[qg][df]) : "v"(pa[qg]), "v"(vf[df]));
    __syncthreads();
    cur ^= 1;
  }
#undef STAGE

  // ---- cross-wave reduction (Ks/Vs reused) ----
  float* Ored  = (float*)&Ks[0][0];   // [64 q][64 d] f32
  float* lpred = (float*)&Vs[0][0];   // [4 w][64 q] f32

  float lpw[4];
#pragma unroll
  for (int qg = 0; qg < 4; ++qg) {
    float v = lp4[qg];
    v += __shfl_xor(v, 16);
    v += __shfl_xor(v, 32);
    lpw[qg] = v;
  }
  if (g == 0) {
#pragma unroll
    for (int qg = 0; qg < 4; ++qg) lpred[w * 64 + qg * 16 + c] = lpw[qg];
  }
  for (int ww = 0; ww < 4; ++ww) {
    if (w == ww) {
#pragma unroll
      for (int qg = 0; qg < 4; ++qg)
#pragma unroll
        for (int df = 0; df < 4; ++df)
#pragma unroll
          for (int r = 0; r < 4; ++r) {
            int q = qg * 16 + 4 * g + r, d = df * 16 + c;
            if (ww == 0) Ored[q * 64 + d] = o[qg][df][r];
            else         Ored[q * 64 + d] += o[qg][df][r];
          }
    }
    __syncthreads();
  }

  float inv[4];
#pragma unroll
  for (int r = 0; r < 4; ++r) {
    int q = w * 16 + g * 4 + r;
    float s = (lpred[q] + lpred[64 + q]) + (lpred[128 + q] + lpred[192 + q]);
    inv[r] = __builtin_amdgcn_rcpf(s);
  }
  int b = bh >> 4, h = bh & 15;
#pragma unroll
  for (int df = 0; df < 4; ++df)
#pragma unroll
    for (int r = 0; r < 4; ++r) {
      int q = w * 16 + g * 4 + r;
      int row = qb * 64 + q;
      int colc = h * 64 + df * 16 + c;
      attn[((size_t)b * 2048 + row) * 1024 + colc] = f2bf(Ored[q * 64 + df * 16 + c] * inv[r]);
    }
}

// ---------------- output projection + bias (fp32 out) ----------------
__global__ __launch_bounds__(256) void proj_gemm(const unsigned short* __restrict__ attn,
                                                 const unsigned short* __restrict__ wpb,
                                                 const float* __restrict__ bias,
                                                 float* __restrict__ out) {
  __shared__ unsigned short As[128 * 32];
  __shared__ unsigned short Bs[128 * 32];
  f32x4 acc[4][4];
#pragma unroll
  for (int i = 0; i < 4; ++i)
#pragma unroll
    for (int j = 0; j < 4; ++j) acc[i][j] = f32x4{0.f, 0.f, 0.f, 0.f};
  int id = (blockIdx.x & 7) * 32 + (blockIdx.x >> 3);  // bijective (256 % 8 == 0)
  int tm = id / 8, tn = id % 8;
  gemm128_bt(attn, wpb, As, Bs, tm, tn, acc);

  int tid = threadIdx.x;
  int w = tid >> 6, l = tid & 63;
  int wr = w >> 1, wc = w & 1;
  int g = l >> 4, c = l & 15;
#pragma unroll
  for (int mi = 0; mi < 4; ++mi)
#pragma unroll
    for (int ni = 0; ni < 4; ++ni)
#pragma unroll
      for (int r = 0; r < 4; ++r) {
        int row = tm * 128 + wr * 64 + mi * 16 + g * 4 + r;
        int col = tn * 128 + wc * 64 + ni * 16 + c;
        out[(size_t)row * 1024 + col] = acc[mi][ni][r] + bias[col];
      }
}

extern "C" void kernel_launch(void* const* d_in, const int* in_sizes, int n_in,
                              void* d_out, int out_size, void* d_ws, size_t ws_size,
                              hipStream_t stream) {
  (void)in_sizes; (void)n_in; (void)out_size; (void)ws_size;
  const float* x      = (const float*)d_in[0];  // [2,2048,1024]
  const float* w_qkv  = (const float*)d_in[1];  // [3072,1024]
  const float* w_proj = (const float*)d_in[2];  // [1024,1024]
  const float* b_proj = (const float*)d_in[3];  // [1024]
  float* out = (float*)d_out;

  unsigned short* xb    = (unsigned short*)d_ws;          // 4096*1024
  unsigned short* wqkvb = xb + 4096 * 1024;               // 3072*1024
  unsigned short* wpb   = wqkvb + 3072 * 1024;            // 1024*1024
  unsigned short* Qp    = wpb + 1024 * 1024;              // 32*2048*64
  unsigned short* Kp    = Qp + 32 * 2048 * 64;            // 32*2048*64
  unsigned short* Vt    = Kp + 32 * 2048 * 64;            // 32*64*2048
  unsigned short* attn  = Vt + 32 * 64 * 2048;            // 4096*1024

  cvt_all<<<1024, 256, 0, stream>>>(x, w_qkv, w_proj, xb);
  qkv_gemm<<<768, 256, 0, stream>>>(xb, wqkvb, Qp, Kp, Vt);
  attn_fa<<<1024, 256, 0, stream>>>(Qp, Kp, Vt, attn);
  proj_gemm<<<256, 256, 0, stream>>>(attn, wpb, b_proj, out);
}